// Round 1
// 428.883 us; speedup vs baseline: 1.0048x; 1.0048x over previous
//
#include <hip/hip_runtime.h>
#include <stdint.h>

#define CATS  32
#define DI    1024
#define DO    1024
#define NB    64
#define ST    512

#define BM 128
#define BN 128
#define BK 32
#define NSTEP (DI / BK)

typedef float  f32x4  __attribute__((ext_vector_type(4)));
typedef short  bf16x8 __attribute__((ext_vector_type(8)));

// v_cvt_pk_bf16_f32: lo -> D[15:0], hi -> D[31:16], RNE rounding (matches f2bf).
__device__ __forceinline__ uint32_t cvt_pk_bf16(float lo, float hi) {
    uint32_t r;
    asm("v_cvt_pk_bf16_f32 %0, %1, %2" : "=v"(r) : "v"(lo), "v"(hi));
    return r;
}

// Single fused kernel: per-category GEMM reading fp32 x and W directly.
// fp32 -> bf16 conversion and the W transpose happen during reg-staged LDS
// writes (scatter is allowed since we do NOT use global_load_lds here).
// LDS layout/swizzle is identical to the previously-verified kernel:
//   element (row, k) lives at row*BK + (k>>3 ^ ((row>>1)&3))*8 + (k&7)
// so the fragment-read + MFMA + epilogue path is carried over unchanged.
__global__ __launch_bounds__(256) void fused_cat_gemm_kernel(
        const float* __restrict__ x, const int* __restrict__ cat_ids,
        const float* __restrict__ W, const float* __restrict__ bias,
        float* __restrict__ out) {
    __shared__ __align__(16) unsigned short As[2][BM * BK];  // 2 x 8 KB
    __shared__ __align__(16) unsigned short Bs[2][BN * BK];  // 2 x 8 KB

    // XCD-aware remap: physical block f runs on XCD f%8; give each XCD a
    // contiguous chunk of 256 work items = 8 whole batch elements, so each
    // b's x-slab (2 MiB) and W[cat] panels stay resident in one XCD's L2.
    const int fb = blockIdx.x;                 // 0..2047
    const int vv = (fb & 7) * 256 + (fb >> 3); // bijective (2048 = 8*256)
    const int b     = vv >> 5;                 // 32 blocks per batch element
    const int mbase = ((vv >> 3) & 3) * BM;    // 4 m-tiles
    const int nbase = (vv & 7) * BN;           // 8 n-tiles (fastest: share A)
    const int cat   = cat_ids[b];

    const int tid  = threadIdx.x;
    const int lane = tid & 63;
    const int w    = tid >> 6;
    const int wr   = w >> 1;       // m half
    const int wc   = w & 1;        // n half
    const int l15  = lane & 15;
    const int kg   = lane >> 4;
    const int koff = (kg ^ ((l15 >> 1) & 3)) * 8;  // swizzled frag k-chunk

    // ---- A staging: thread loads 4 f32x4 of x (rows am+32q, cols ak..ak+3).
    // Wave = 8 rows x 128 B contiguous per load: fully coalesced.
    const int am   = tid >> 3;            // 0..31
    const int ak   = (tid & 7) * 4;       // 0..28
    const int ac   = (ak >> 3) ^ ((am >> 1) & 3);    // (am>>1)&3 invariant to +32q
    const int aoff = am * BK + ac * 8 + (ak & 4);    // ushort units; +q*32*BK
    const float* gA = x + (size_t)(b * ST + mbase + am) * DI + ak;

    // ---- B staging: thread loads two adjacent W rows (k=2*k2, k=2*k2+1) at
    // one n-quad; cross-packs into Bs[n][k] (transpose via write addressing).
    // Wave = 2x (512 B contiguous) per row: fully coalesced.
    const int nq  = tid & 31;             // n quad: n = 4*nq..4*nq+3
    const int k2b = tid >> 5;             // 0..7 (k-pair base; +8u)
    const float* gB = W + (size_t)cat * DI * DO + nbase + nq * 4;

    f32x4 acc[4][4];
    #pragma unroll
    for (int mi = 0; mi < 4; ++mi)
        #pragma unroll
        for (int ni = 0; ni < 4; ++ni)
            acc[mi][ni] = (f32x4){0.f, 0.f, 0.f, 0.f};

    f32x4 ra[4];           // x tile in flight
    f32x4 rb0[2], rb1[2];  // W row pairs in flight

    auto LOADS = [&](int step) {
        #pragma unroll
        for (int q = 0; q < 4; ++q)
            ra[q] = *(const f32x4*)(gA + (size_t)q * 32 * DI + step * BK);
        #pragma unroll
        for (int u = 0; u < 2; ++u) {
            const float* p = gB + (size_t)(step * BK + (k2b + 8 * u) * 2) * DO;
            rb0[u] = *(const f32x4*)p;
            rb1[u] = *(const f32x4*)(p + DO);
        }
    };

    auto WRITES = [&](int bufi) {
        #pragma unroll
        for (int q = 0; q < 4; ++q) {
            uint2 pk;
            pk.x = cvt_pk_bf16(ra[q][0], ra[q][1]);
            pk.y = cvt_pk_bf16(ra[q][2], ra[q][3]);
            *(uint2*)&As[bufi][aoff + q * 32 * BK] = pk;   // 8B, 8B-aligned
        }
        #pragma unroll
        for (int u = 0; u < 2; ++u) {
            const int k2 = k2b + 8 * u;                    // k = 2*k2
            #pragma unroll
            for (int j = 0; j < 4; ++j) {
                const int n = nq * 4 + j;
                const int c = (k2 >> 2) ^ ((n >> 1) & 3);
                *(uint32_t*)&Bs[bufi][n * BK + c * 8 + (k2 & 3) * 2] =
                    cvt_pk_bf16(rb0[u][j], rb1[u][j]);     // {W[k][n], W[k+1][n]}
            }
        }
    };

    LOADS(0);
    WRITES(0);
    __syncthreads();

    int buf = 0;
    #pragma unroll 1
    for (int step = 0; step < NSTEP; ++step) {
        if (step + 1 < NSTEP)
            LOADS(step + 1);           // issue early; vmcnt hides under MFMA

        bf16x8 af[4], bfr[4];
        #pragma unroll
        for (int mi = 0; mi < 4; ++mi)
            af[mi] = *(const bf16x8*)&As[buf][(wr * 64 + mi * 16 + l15) * BK + koff];
        #pragma unroll
        for (int ni = 0; ni < 4; ++ni)
            bfr[ni] = *(const bf16x8*)&Bs[buf][(wc * 64 + ni * 16 + l15) * BK + koff];

        #pragma unroll
        for (int mi = 0; mi < 4; ++mi)
            #pragma unroll
            for (int ni = 0; ni < 4; ++ni)
                acc[mi][ni] = __builtin_amdgcn_mfma_f32_16x16x32_bf16(
                                  af[mi], bfr[ni], acc[mi][ni], 0, 0, 0);

        if (step + 1 < NSTEP)
            WRITES(buf ^ 1);           // write late; buf^1 drained at last barrier

        __syncthreads();               // publishes buf^1; buf fully consumed
        buf ^= 1;
    }

    // Epilogue (unchanged, verified): D col = l15 (n), row = kg*4 + r (m).
    float bsv[4];
    #pragma unroll
    for (int ni = 0; ni < 4; ++ni)
        bsv[ni] = bias[(size_t)cat * DO + nbase + wc * 64 + ni * 16 + l15];

    #pragma unroll
    for (int mi = 0; mi < 4; ++mi) {
        const int rowb = mbase + wr * 64 + mi * 16 + kg * 4;
        #pragma unroll
        for (int r = 0; r < 4; ++r) {
            float* orow = out + (size_t)(b * ST + rowb + r) * DO
                              + nbase + wc * 64 + l15;
            #pragma unroll
            for (int ni = 0; ni < 4; ++ni)
                orow[ni * 16] = acc[mi][ni][r] + bsv[ni];
        }
    }
}

extern "C" void kernel_launch(void* const* d_in, const int* in_sizes, int n_in,
                              void* d_out, int out_size, void* d_ws, size_t ws_size,
                              hipStream_t stream) {
    const float* x    = (const float*)d_in[0];
    const int*   cats = (const int*)d_in[1];
    const float* W    = (const float*)d_in[2];
    const float* bias = (const float*)d_in[3];
    float*       out  = (float*)d_out;

    (void)d_ws; (void)ws_size;  // no workspace: fully fused single pass

    fused_cat_gemm_kernel<<<NB * (ST / BM) * (DO / BN), 256, 0, stream>>>(
        x, cats, W, bias, out);
}

// Round 2
// 427.959 us; speedup vs baseline: 1.0070x; 1.0022x over previous
//
#include <hip/hip_runtime.h>
#include <stdint.h>

#define CATS  32
#define DI    1024
#define DO    1024
#define NB    64
#define ST    512

#define BM 128
#define BN 128
#define BK 32
#define NSTEP (DI / BK)

typedef float  f32x4  __attribute__((ext_vector_type(4)));
typedef short  bf16x8 __attribute__((ext_vector_type(8)));

// v_cvt_pk_bf16_f32: lo -> D[15:0], hi -> D[31:16], RNE (matches reference path).
__device__ __forceinline__ uint32_t cvt_pk_bf16(float lo, float hi) {
    uint32_t r;
    asm("v_cvt_pk_bf16_f32 %0, %1, %2" : "=v"(r) : "v"(lo), "v"(hi));
    return r;
}

// In-flight register tile: 4x 16B of x, 2x2x 16B of W (two adjacent k-rows).
struct Regs {
    f32x4 ra[4];
    f32x4 rb0[2], rb1[2];
};

// Fused per-category GEMM, fp32 in / fp32 out, bf16 MFMA internally.
// LDS layout (both A and B): element (row,k) at row*BK + ((k>>3)^((row>>1)&3))*8 + (k&7)
// (identical to the verified kernel; fragment-read + MFMA + epilogue unchanged).
//
// Round-2 changes vs round-1:
//  * B-staging lane remap (bq=tid>>3, k2=lane&7): ds_write_b32 bank spread
//    16-way -> 4-way (bank = 16*(n&1) + 4*c + (k2&3); lane bits 0..3 now
//    drive (k2&3) and c).
//  * 2-deep register prefetch + raw s_barrier with lgkmcnt(0) only (no
//    vmcnt(0) drain): loads for step s+2 stay in flight across barriers;
//    compiler emits counted vmcnt before WRITES uses the older reg set.
__global__ __launch_bounds__(256, 2) void fused_cat_gemm_kernel(
        const float* __restrict__ x, const int* __restrict__ cat_ids,
        const float* __restrict__ W, const float* __restrict__ bias,
        float* __restrict__ out) {
    __shared__ __align__(16) unsigned short As[2][BM * BK];  // 2 x 8 KB
    __shared__ __align__(16) unsigned short Bs[2][BN * BK];  // 2 x 8 KB

    // XCD-aware remap (bijective, 2048 = 8*256): each XCD gets 8 whole batch
    // elements -> x-slab + W[cat] panels L2-local.
    const int fb = blockIdx.x;
    const int vv = (fb & 7) * 256 + (fb >> 3);
    const int b     = vv >> 5;
    const int mbase = ((vv >> 3) & 3) * BM;
    const int nbase = (vv & 7) * BN;
    const int cat   = cat_ids[b];

    const int tid  = threadIdx.x;
    const int lane = tid & 63;
    const int w    = tid >> 6;
    const int wr   = w >> 1;
    const int wc   = w & 1;
    const int l15  = lane & 15;
    const int kg   = lane >> 4;
    const int koff = (kg ^ ((l15 >> 1) & 3)) * 8;

    // ---- A staging: 4x f32x4 of x (rows am+32q, cols ak..ak+3), 8 rows x
    // 128 B contiguous per wave-load. LDS write: uint2 (4 bf16), ~4-way max.
    const int am   = tid >> 3;
    const int ak   = (tid & 7) * 4;
    const int ac   = (ak >> 3) ^ ((am >> 1) & 3);
    const int aoff = am * BK + ac * 8 + (ak & 4);
    const float* gA = x + (size_t)(b * ST + mbase + am) * DI + ak;

    // ---- B staging: n-quad bq = tid>>3, k-pair base bk2 = lane&7 (+8u).
    // Per row: 8 lanes x 16B = 128 B contiguous. Write: cross-packed
    // ds_write_b32 into Bs[n][k]; bank = 16*(n&1)+4*c+(k2&3) -> 16 distinct
    // banks per instruction (4-way).
    const int bq  = tid >> 3;
    const int bk2 = lane & 7;
    const float* gB = W + (size_t)cat * DI * DO + nbase + bq * 4;

    f32x4 acc[4][4];
    #pragma unroll
    for (int mi = 0; mi < 4; ++mi)
        #pragma unroll
        for (int ni = 0; ni < 4; ++ni)
            acc[mi][ni] = (f32x4){0.f, 0.f, 0.f, 0.f};

    auto LOADS = [&](Regs& R, int step) {
        #pragma unroll
        for (int q = 0; q < 4; ++q)
            R.ra[q] = *(const f32x4*)(gA + (size_t)q * 32 * DI + step * BK);
        #pragma unroll
        for (int u = 0; u < 2; ++u) {
            const float* p = gB + (size_t)(step * BK + (bk2 + 8 * u) * 2) * DO;
            R.rb0[u] = *(const f32x4*)p;
            R.rb1[u] = *(const f32x4*)(p + DO);
        }
    };

    auto WRITES = [&](int bufi, Regs& R) {
        #pragma unroll
        for (int q = 0; q < 4; ++q) {
            uint2 pk;
            pk.x = cvt_pk_bf16(R.ra[q][0], R.ra[q][1]);
            pk.y = cvt_pk_bf16(R.ra[q][2], R.ra[q][3]);
            *(uint2*)&As[bufi][aoff + q * 32 * BK] = pk;
        }
        #pragma unroll
        for (int u = 0; u < 2; ++u) {
            const int k2 = bk2 + 8 * u;
            #pragma unroll
            for (int j = 0; j < 4; ++j) {
                const int n = bq * 4 + j;
                const int c = ((k2 >> 2) ^ (n >> 1)) & 3;
                *(uint32_t*)&Bs[bufi][n * BK + c * 8 + (k2 & 3) * 2] =
                    cvt_pk_bf16(R.rb0[u][j], R.rb1[u][j]);  // {W[k][n], W[k+1][n]}
            }
        }
    };

    auto MFMA_STEP = [&](int bufc) {
        bf16x8 af[4], bfr[4];
        #pragma unroll
        for (int mi = 0; mi < 4; ++mi)
            af[mi] = *(const bf16x8*)&As[bufc][(wr * 64 + mi * 16 + l15) * BK + koff];
        #pragma unroll
        for (int ni = 0; ni < 4; ++ni)
            bfr[ni] = *(const bf16x8*)&Bs[bufc][(wc * 64 + ni * 16 + l15) * BK + koff];
        #pragma unroll
        for (int mi = 0; mi < 4; ++mi)
            #pragma unroll
            for (int ni = 0; ni < 4; ++ni)
                acc[mi][ni] = __builtin_amdgcn_mfma_f32_16x16x32_bf16(
                                  af[mi], bfr[ni], acc[mi][ni], 0, 0, 0);
    };

    #define LGKM_BARRIER()                                      \
        do {                                                    \
            asm volatile("s_waitcnt lgkmcnt(0)" ::: "memory");  \
            __builtin_amdgcn_s_barrier();                       \
        } while (0)

    Regs r0, r1;
    // Prologue: tile0 -> LDS[0]; tile1 loads in flight in r1.
    LOADS(r0, 0);
    WRITES(0, r0);
    LOADS(r1, 1);
    LGKM_BARRIER();

    // Steady state (2x unrolled so reg-set indexing is static — rule #20):
    //   sub A: issue loads(s+2)->r0 | MFMA on buf0 | write tile s+1 from r1
    //   sub B: issue loads(s+3)->r1 | MFMA on buf1 | write tile s+2 from r0
    // Barriers carry only lgkmcnt(0); in-flight global loads cross them.
    #pragma unroll 1
    for (int s = 0; s < NSTEP; s += 2) {
        if (s + 2 < NSTEP) LOADS(r0, s + 2);
        MFMA_STEP(0);
        WRITES(1, r1);                 // s+1 <= 31 always
        LGKM_BARRIER();

        if (s + 3 < NSTEP) LOADS(r1, s + 3);
        MFMA_STEP(1);
        if (s + 2 < NSTEP) WRITES(0, r0);
        LGKM_BARRIER();
    }
    #undef LGKM_BARRIER

    // Epilogue (verified): D col = l15 (n), row = kg*4 + r (m).
    float bsv[4];
    #pragma unroll
    for (int ni = 0; ni < 4; ++ni)
        bsv[ni] = bias[(size_t)cat * DO + nbase + wc * 64 + ni * 16 + l15];

    #pragma unroll
    for (int mi = 0; mi < 4; ++mi) {
        const int rowb = mbase + wr * 64 + mi * 16 + kg * 4;
        #pragma unroll
        for (int r = 0; r < 4; ++r) {
            float* orow = out + (size_t)(b * ST + rowb + r) * DO
                              + nbase + wc * 64 + l15;
            #pragma unroll
            for (int ni = 0; ni < 4; ++ni)
                orow[ni * 16] = acc[mi][ni][r] + bsv[ni];
        }
    }
}

extern "C" void kernel_launch(void* const* d_in, const int* in_sizes, int n_in,
                              void* d_out, int out_size, void* d_ws, size_t ws_size,
                              hipStream_t stream) {
    const float* x    = (const float*)d_in[0];
    const int*   cats = (const int*)d_in[1];
    const float* W    = (const float*)d_in[2];
    const float* bias = (const float*)d_in[3];
    float*       out  = (float*)d_out;

    (void)d_ws; (void)ws_size;  // fully fused single pass, no workspace

    fused_cat_gemm_kernel<<<NB * (ST / BM) * (DO / BN), 256, 0, stream>>>(
        x, cats, W, bias, out);
}